// Round 1
// baseline (373.493 us; speedup 1.0000x reference)
//
#include <hip/hip_runtime.h>

#define D   2048
#define NB  32
#define BD  64
#define HD  128
#define RT  32          // batch rows per workgroup
#define NTH 512         // threads per workgroup (8 waves)

typedef __attribute__((ext_vector_type(8))) short  short8;
typedef __attribute__((ext_vector_type(4))) float  floatx4;

__device__ __forceinline__ unsigned short f2bf(float f) {
  union { float f; unsigned u; } v; v.f = f;
  return (unsigned short)((v.u + 0x7FFFu + ((v.u >> 16) & 1u)) >> 16);
}
__device__ __forceinline__ float bf2f(unsigned short h) {
  union { unsigned u; float f; } v; v.u = ((unsigned)h) << 16;
  return v.f;
}
__device__ __forceinline__ float fast_exp2(float x) {
  float r; asm("v_exp_f32 %0, %1" : "=v"(r) : "v"(x)); return r;
}
__device__ __forceinline__ float fast_rcp(float x) {
  float r; asm("v_rcp_f32 %0, %1" : "=v"(r) : "v"(x)); return r;
}
// sigmoid-form tanh-approx GELU; |diff vs erf-GELU| < ~3e-3 absolute per elem
__device__ __forceinline__ float gelu_f(float x) {
  float x2 = x * x;
  float w  = __builtin_fmaf(x2, 0.044715f, 1.0f);
  float e  = fast_exp2(x * w * -2.3022083f);   // -2*log2(e)*sqrt(2/pi)
  return x * fast_rcp(1.0f + e);
}

// XOR bank-conflict swizzle (byte ^= (row&7)<<4), expressed in short-index units
__device__ __forceinline__ int y0i(int row, int col) {
  return row * D + (col ^ ((row & 7) << 3));
}
__device__ __forceinline__ int hsi(int row, int col) {
  return row * HD + (col ^ ((row & 7) << 3));
}

// W [n][R][C] f32  ->  Wt [n][C][R] bf16   (so MFMA A-frags are contiguous 16B)
__global__ void prep_w(const float* __restrict__ W, unsigned short* __restrict__ Wt,
                       int R, int C) {
  int id  = blockIdx.x * 256 + threadIdx.x;
  int n   = id / (R * C);
  int rem = id - n * (R * C);
  int c   = rem / R;
  int r   = rem - c * R;
  Wt[id] = f2bf(W[(n * R + r) * C + c]);
}

__device__ void do_layer(unsigned short* Y0, unsigned short* Hs,
                         const unsigned short* __restrict__ W1t,
                         const unsigned short* __restrict__ W2t,
                         const float* __restrict__ b1,
                         const float* __restrict__ b2) {
  const int t    = threadIdx.x;
  const int w    = t >> 6;
  const int l    = t & 63;
  const int bt   = w & 1;        // batch half-tile (16 rows)
  const int pair = w >> 1;       // 0..3, owns blocks [pair*8, pair*8+8)
  unsigned short* Hp = Hs + pair * (RT * HD);
  const int lr   = l & 15;
  const int q    = l >> 4;       // 0..3
  const int brow = bt * 16 + lr; // this lane's batch row (N-dim of swapped MFMA)

  for (int nb = 0; nb < 8; ++nb) {
    const int n = pair * 8 + nb;

    // ---- GEMM1' : H^T = W1[n]^T (128x64) @ X_blk^T (64x16) ----
    short8 xb0 = *(const short8*)&Y0[y0i(brow, n * BD + 0  + q * 8)];
    short8 xb1 = *(const short8*)&Y0[y0i(brow, n * BD + 32 + q * 8)];
    floatx4 zero = {0.f, 0.f, 0.f, 0.f};
    floatx4 acc1[8];
#pragma unroll
    for (int ot = 0; ot < 8; ++ot) acc1[ot] = zero;
#pragma unroll
    for (int ot = 0; ot < 8; ++ot) {
      short8 a0 = *(const short8*)&W1t[(n * HD + ot * 16 + lr) * BD + 0  + q * 8];
      short8 a1 = *(const short8*)&W1t[(n * HD + ot * 16 + lr) * BD + 32 + q * 8];
      acc1[ot] = __builtin_amdgcn_mfma_f32_16x16x32_bf16(a0, xb0, acc1[ot], 0, 0, 0);
      acc1[ot] = __builtin_amdgcn_mfma_f32_16x16x32_bf16(a1, xb1, acc1[ot], 0, 0, 0);
    }
    // bias + gelu, write H row-major [batch][o] (4 consecutive o per lane -> b64)
#pragma unroll
    for (int ot = 0; ot < 8; ++ot) {
      const float4 bb = *(const float4*)&b1[n * HD + ot * 16 + q * 4];
      ushort4 hv;
      hv.x = f2bf(gelu_f(acc1[ot][0] + bb.x));
      hv.y = f2bf(gelu_f(acc1[ot][1] + bb.y));
      hv.z = f2bf(gelu_f(acc1[ot][2] + bb.z));
      hv.w = f2bf(gelu_f(acc1[ot][3] + bb.w));
      *(ushort4*)&Hp[hsi(brow, ot * 16 + q * 4)] = hv;
    }

    // ---- GEMM2' : O^T = W2[n]^T (64x128) @ H^T (128x16) ----
    short8 hb[4];
#pragma unroll
    for (int ks = 0; ks < 4; ++ks)
      hb[ks] = *(const short8*)&Hp[hsi(brow, ks * 32 + q * 8)];
    floatx4 acc2[4];
#pragma unroll
    for (int ot = 0; ot < 4; ++ot) acc2[ot] = zero;
#pragma unroll
    for (int ot = 0; ot < 4; ++ot) {
#pragma unroll
      for (int ks = 0; ks < 4; ++ks) {
        short8 a = *(const short8*)&W2t[(n * BD + ot * 16 + lr) * HD + ks * 32 + q * 8];
        acc2[ot] = __builtin_amdgcn_mfma_f32_16x16x32_bf16(a, hb[ks], acc2[ot], 0, 0, 0);
      }
    }
#pragma unroll
    for (int ot = 0; ot < 4; ++ot) {
      const float4 bb = *(const float4*)&b2[n * BD + ot * 16 + q * 4];
      ushort4 ov;
      ov.x = f2bf(acc2[ot][0] + bb.x);
      ov.y = f2bf(acc2[ot][1] + bb.y);
      ov.z = f2bf(acc2[ot][2] + bb.z);
      ov.w = f2bf(acc2[ot][3] + bb.w);
      *(ushort4*)&Y0[y0i(brow, n * BD + ot * 16 + q * 4)] = ov;   // in-place
    }
  }
}

// In-place 64x64 transpose of each 4096-element group (2 batch rows) in Y0
__device__ void transpose_groups(unsigned short* Y0) {
  const int t  = threadIdx.x;
  const int r  = t >> 3;         // 0..63
  const int c0 = (t & 7) * 8;    // 0,8,...,56
  __syncthreads();
  for (int gl = 0; gl < 16; ++gl) {
    short8 v = *(const short8*)&Y0[y0i(2 * gl + (r >> 5), (r & 31) * 64 + c0)];
    __syncthreads();
#pragma unroll
    for (int i = 0; i < 8; ++i) {
      const int c = c0 + i;
      Y0[y0i(2 * gl + (c >> 5), (c & 31) * 64 + r)] = (unsigned short)v[i];
    }
    __syncthreads();
  }
}

__global__ __launch_bounds__(NTH, 2) void fused_mixer(
    const float* __restrict__ x,
    const unsigned short* __restrict__ W1t0, const unsigned short* __restrict__ W2t0,
    const float* __restrict__ b1_0, const float* __restrict__ b2_0,
    const unsigned short* __restrict__ W1t1, const unsigned short* __restrict__ W2t1,
    const float* __restrict__ b1_1, const float* __restrict__ b2_1,
    float* __restrict__ out) {
  __shared__ unsigned short Y0[RT * D];        // 128 KiB
  __shared__ unsigned short Hs[4 * RT * HD];   //  32 KiB (one per wave-pair)
  const long long base = (long long)blockIdx.x * (RT * D);
  const int t = threadIdx.x;

  // stage x -> bf16 LDS (coalesced float4)
#pragma unroll
  for (int it = 0; it < (RT * D) / (NTH * 4); ++it) {
    const int idx = (it * NTH + t) * 4;
    const float4 v = *(const float4*)(x + base + idx);
    ushort4 p;
    p.x = f2bf(v.x); p.y = f2bf(v.y); p.z = f2bf(v.z); p.w = f2bf(v.w);
    *(ushort4*)&Y0[y0i(idx >> 11, idx & (D - 1))] = p;
  }
  __syncthreads();

  do_layer(Y0, Hs, W1t0, W2t0, b1_0, b2_0);   // layer 0 (pre/post permute = identity)
  transpose_groups(Y0);                        // layer-1 pre-permute
  do_layer(Y0, Hs, W1t1, W2t1, b1_1, b2_1);   // layer 1
  transpose_groups(Y0);                        // layer-1 post-permute

  // store bf16 -> f32 (coalesced)
#pragma unroll
  for (int it = 0; it < (RT * D) / (NTH * 8); ++it) {
    const int idx = (it * NTH + t) * 8;
    short8 v = *(const short8*)&Y0[y0i(idx >> 11, idx & (D - 1))];
    float4 f0, f1;
    f0.x = bf2f((unsigned short)v[0]); f0.y = bf2f((unsigned short)v[1]);
    f0.z = bf2f((unsigned short)v[2]); f0.w = bf2f((unsigned short)v[3]);
    f1.x = bf2f((unsigned short)v[4]); f1.y = bf2f((unsigned short)v[5]);
    f1.z = bf2f((unsigned short)v[6]); f1.w = bf2f((unsigned short)v[7]);
    *(float4*)(out + base + idx)     = f0;
    *(float4*)(out + base + idx + 4) = f1;
  }
}

extern "C" void kernel_launch(void* const* d_in, const int* in_sizes, int n_in,
                              void* d_out, int out_size, void* d_ws, size_t ws_size,
                              hipStream_t stream) {
  const float* x    = (const float*)d_in[0];
  const float* W1_0 = (const float*)d_in[1];
  const float* b1_0 = (const float*)d_in[2];
  const float* W2_0 = (const float*)d_in[3];
  const float* b2_0 = (const float*)d_in[4];
  const float* W1_1 = (const float*)d_in[5];
  const float* b1_1 = (const float*)d_in[6];
  const float* W2_1 = (const float*)d_in[7];
  const float* b2_1 = (const float*)d_in[8];
  float* out = (float*)d_out;

  const int WSZ = NB * HD * BD;               // 262144 elems per weight matrix
  unsigned short* W1t0 = (unsigned short*)d_ws;
  unsigned short* W2t0 = W1t0 + WSZ;
  unsigned short* W1t1 = W2t0 + WSZ;
  unsigned short* W2t1 = W1t1 + WSZ;

  prep_w<<<WSZ / 256, 256, 0, stream>>>(W1_0, W1t0, BD, HD);
  prep_w<<<WSZ / 256, 256, 0, stream>>>(W2_0, W2t0, HD, BD);
  prep_w<<<WSZ / 256, 256, 0, stream>>>(W1_1, W1t1, BD, HD);
  prep_w<<<WSZ / 256, 256, 0, stream>>>(W2_1, W2t1, HD, BD);

  fused_mixer<<<16384 / RT, NTH, 0, stream>>>(
      x, W1t0, W2t0, b1_0, b2_0, W1t1, W2t1, b1_1, b2_1, out);
}

// Round 2
// 304.043 us; speedup vs baseline: 1.2284x; 1.2284x over previous
//
#include <hip/hip_runtime.h>

#define D    2048
#define NB   32
#define BD   64
#define HD   128
#define RT   16          // batch rows per workgroup (8 groups of 2)
#define NTH  512         // 8 waves; each wave owns 4 blocks x 16 rows
#define WSZ  (NB * HD * BD)   // 262144 elems per weight matrix

typedef __attribute__((ext_vector_type(8))) short short8;
typedef __attribute__((ext_vector_type(4))) float floatx4;

static __device__ __forceinline__ unsigned short f2bf(float f) {
  union { float f; unsigned u; } v; v.f = f;
  return (unsigned short)((v.u + 0x7FFFu + ((v.u >> 16) & 1u)) >> 16);
}
static __device__ __forceinline__ float bf2f(unsigned short h) {
  union { unsigned u; float f; } v; v.u = ((unsigned)h) << 16;
  return v.f;
}
static __device__ __forceinline__ float fast_exp2(float x) {
  float r; asm("v_exp_f32 %0, %1" : "=v"(r) : "v"(x)); return r;
}
static __device__ __forceinline__ float fast_rcp(float x) {
  float r; asm("v_rcp_f32 %0, %1" : "=v"(r) : "v"(x)); return r;
}
// sigmoid-form tanh-approx GELU (validated round 1: absmax 136 < 586)
static __device__ __forceinline__ float gelu_f(float x) {
  float x2 = x * x;
  float w  = __builtin_fmaf(x2, 0.044715f, 1.0f);
  float e  = fast_exp2(x * w * -2.3022083f);
  return x * fast_rcp(1.0f + e);
}

// Y [RT][D] bf16: XOR swizzle over bits 3-5 (16B granules) keyed on row and
// col bits 8-9 (=q at scatter time) -> ~8-way max conflict on scalar scatter,
// standard conflict-free-ish pattern on ds_read_b128. Bijective per row.
static __device__ __forceinline__ int ys(int row, int col) {
  return row * D + (col ^ ((row & 7) << 3) ^ (((col >> 8) & 3) << 3));
}
// H chunk [16][64] bf16 per wave
static __device__ __forceinline__ int hsw(int row, int col) {
  return row * 64 + (col ^ ((row & 7) << 3));
}

// One block-MLP (both GEMMs, gelu, bias) for 16 rows, swapped-operand MFMA.
// Output scattered into Y at group-transposed positions (the layer-1
// pre-permute == layer-1 post-permute == 64x64 transpose within 2-row groups).
static __device__ __forceinline__ void mlp_block(
    short8 xb0, short8 xb1, int n, int lr, int q,
    const unsigned short* __restrict__ W1t, const unsigned short* __restrict__ W2t,
    const float* __restrict__ b1, const float* __restrict__ b2,
    unsigned short* Hp, unsigned short* Y) {
  const floatx4 zero = {0.f, 0.f, 0.f, 0.f};
  floatx4 acc2[4] = {zero, zero, zero, zero};
#pragma unroll
  for (int half = 0; half < 2; ++half) {       // H features in 64-wide chunks
    floatx4 acc1[4] = {zero, zero, zero, zero};
#pragma unroll
    for (int ot = 0; ot < 4; ++ot) {
      const unsigned short* wr = &W1t[(n * HD + half * 64 + ot * 16 + lr) * BD + q * 8];
      short8 a0 = *(const short8*)(wr);
      short8 a1 = *(const short8*)(wr + 32);
      acc1[ot] = __builtin_amdgcn_mfma_f32_16x16x32_bf16(a0, xb0, acc1[ot], 0, 0, 0);
      acc1[ot] = __builtin_amdgcn_mfma_f32_16x16x32_bf16(a1, xb1, acc1[ot], 0, 0, 0);
    }
#pragma unroll
    for (int ot = 0; ot < 4; ++ot) {
      const float4 bb = *(const float4*)&b1[n * HD + half * 64 + ot * 16 + q * 4];
      ushort4 hv;
      hv.x = f2bf(gelu_f(acc1[ot][0] + bb.x));
      hv.y = f2bf(gelu_f(acc1[ot][1] + bb.y));
      hv.z = f2bf(gelu_f(acc1[ot][2] + bb.z));
      hv.w = f2bf(gelu_f(acc1[ot][3] + bb.w));
      *(ushort4*)&Hp[hsw(lr, ot * 16 + q * 4)] = hv;
    }
    // in-wave RAW through LDS (in-order DS pipe; validated round 1)
    short8 hb0 = *(const short8*)&Hp[hsw(lr, q * 8)];
    short8 hb1 = *(const short8*)&Hp[hsw(lr, 32 + q * 8)];
#pragma unroll
    for (int ot = 0; ot < 4; ++ot) {
      const unsigned short* wr2 = &W2t[(n * BD + ot * 16 + lr) * HD + half * 64 + q * 8];
      short8 c0 = *(const short8*)(wr2);
      short8 c1 = *(const short8*)(wr2 + 32);
      acc2[ot] = __builtin_amdgcn_mfma_f32_16x16x32_bf16(c0, hb0, acc2[ot], 0, 0, 0);
      acc2[ot] = __builtin_amdgcn_mfma_f32_16x16x32_bf16(c1, hb1, acc2[ot], 0, 0, 0);
    }
  }
  // bias + permuted scatter: orig (row lr, col n*64+f) -> permuted
  // (row (lr&~1)|(f>>5), col (f&31)*64 + (lr&1)*32 + n)
#pragma unroll
  for (int ot = 0; ot < 4; ++ot) {
    const float4 bb = *(const float4*)&b2[n * BD + ot * 16 + q * 4];
#pragma unroll
    for (int e = 0; e < 4; ++e) {
      const int f = ot * 16 + q * 4 + e;
      const int trow = (lr & ~1) | (f >> 5);
      const int tcol = ((f & 31) << 6) + ((lr & 1) << 5) + n;
      const float bv = (e == 0) ? bb.x : (e == 1) ? bb.y : (e == 2) ? bb.z : bb.w;
      Y[ys(trow, tcol)] = f2bf(acc2[ot][e] + bv);
    }
  }
}

__global__ __launch_bounds__(NTH, 4) void fused_mixer(
    const float* __restrict__ x,
    const unsigned short* __restrict__ W1t0, const unsigned short* __restrict__ W2t0,
    const float* __restrict__ b1_0, const float* __restrict__ b2_0,
    const unsigned short* __restrict__ W1t1, const unsigned short* __restrict__ W2t1,
    const float* __restrict__ b1_1, const float* __restrict__ b2_1,
    float* __restrict__ out) {
  __shared__ unsigned short Y[RT * D];        // 64 KiB
  __shared__ unsigned short Hs[8 * 16 * 64];  // 16 KiB (2 KiB per wave)
  const int t  = threadIdx.x;
  const int wv = t >> 6;
  const int l  = t & 63;
  const int lr = l & 15;        // MFMA N dim = batch/permuted row
  const int q  = l >> 4;        // k-chunk / acc-row group
  unsigned short* Hp = Hs + wv * (16 * 64);
  const long long R0 = (long long)blockIdx.x * RT;

  // ---- layer 0: B-frags straight from global x (f32 -> bf16) ----
  for (int bi = 0; bi < 4; ++bi) {
    const int n = wv * 4 + bi;
    const float* xr = x + (R0 + lr) * D + n * BD + q * 8;
    const float4 u0 = *(const float4*)(xr);
    const float4 u1 = *(const float4*)(xr + 4);
    const float4 u2 = *(const float4*)(xr + 32);
    const float4 u3 = *(const float4*)(xr + 36);
    short8 xb0, xb1;
    xb0[0] = f2bf(u0.x); xb0[1] = f2bf(u0.y); xb0[2] = f2bf(u0.z); xb0[3] = f2bf(u0.w);
    xb0[4] = f2bf(u1.x); xb0[5] = f2bf(u1.y); xb0[6] = f2bf(u1.z); xb0[7] = f2bf(u1.w);
    xb1[0] = f2bf(u2.x); xb1[1] = f2bf(u2.y); xb1[2] = f2bf(u2.z); xb1[3] = f2bf(u2.w);
    xb1[4] = f2bf(u3.x); xb1[5] = f2bf(u3.y); xb1[6] = f2bf(u3.z); xb1[7] = f2bf(u3.w);
    mlp_block(xb0, xb1, n, lr, q, W1t0, W2t0, b1_0, b2_0, Hp, Y);
  }
  __syncthreads();   // permuted Y complete

  // ---- layer 1: preload all B-frags (in-place hazard), then compute ----
  short8 xf[8];
#pragma unroll
  for (int bi = 0; bi < 4; ++bi) {
    const int n = wv * 4 + bi;
    xf[2 * bi]     = *(const short8*)&Y[ys(lr, n * BD + q * 8)];
    xf[2 * bi + 1] = *(const short8*)&Y[ys(lr, n * BD + 32 + q * 8)];
  }
  __syncthreads();   // all reads done before any wave scatters
#pragma unroll
  for (int bi = 0; bi < 4; ++bi) {
    const int n = wv * 4 + bi;
    mlp_block(xf[2 * bi], xf[2 * bi + 1], n, lr, q, W1t1, W2t1, b1_1, b2_1, Hp, Y);
  }
  __syncthreads();   // final-layout Y complete

  // ---- coalesced store: Y bf16 -> f32 out ----
#pragma unroll
  for (int it = 0; it < (RT * D) / (NTH * 8); ++it) {   // 8 iters
    const int idx = (it * NTH + t) * 8;
    const int row = idx >> 11, col = idx & (D - 1);
    short8 v = *(const short8*)&Y[ys(row, col)];
    float4 f0, f1;
    f0.x = bf2f((unsigned short)v[0]); f0.y = bf2f((unsigned short)v[1]);
    f0.z = bf2f((unsigned short)v[2]); f0.w = bf2f((unsigned short)v[3]);
    f1.x = bf2f((unsigned short)v[4]); f1.y = bf2f((unsigned short)v[5]);
    f1.z = bf2f((unsigned short)v[6]); f1.w = bf2f((unsigned short)v[7]);
    *(float4*)(out + R0 * D + idx)     = f0;
    *(float4*)(out + R0 * D + idx + 4) = f1;
  }
}

// W [n][R][C] f32 -> Wt [n][C][R] bf16, all four matrices in one launch
__global__ void prep_w_all(const float* __restrict__ W1_0, const float* __restrict__ W2_0,
                           const float* __restrict__ W1_1, const float* __restrict__ W2_1,
                           unsigned short* __restrict__ dst) {
  const int seg = blockIdx.x >> 10;                       // 1024 blocks/segment
  const int id  = ((blockIdx.x & 1023) << 8) | threadIdx.x;  // [0, 262144)
  const float* W; int R;
  if      (seg == 0) { W = W1_0; R = BD; }
  else if (seg == 1) { W = W2_0; R = HD; }
  else if (seg == 2) { W = W1_1; R = BD; }
  else               { W = W2_1; R = HD; }
  const int C   = (R == BD) ? HD : BD;
  const int n   = id >> 13;          // R*C == 8192
  const int rem = id & 8191;
  const int c   = rem / R;
  const int r   = rem - c * R;
  dst[seg * WSZ + id] = f2bf(W[(n * R + r) * C + c]);
}

extern "C" void kernel_launch(void* const* d_in, const int* in_sizes, int n_in,
                              void* d_out, int out_size, void* d_ws, size_t ws_size,
                              hipStream_t stream) {
  const float* x    = (const float*)d_in[0];
  const float* W1_0 = (const float*)d_in[1];
  const float* b1_0 = (const float*)d_in[2];
  const float* W2_0 = (const float*)d_in[3];
  const float* b2_0 = (const float*)d_in[4];
  const float* W1_1 = (const float*)d_in[5];
  const float* b1_1 = (const float*)d_in[6];
  const float* W2_1 = (const float*)d_in[7];
  const float* b2_1 = (const float*)d_in[8];
  float* out = (float*)d_out;

  unsigned short* Wt = (unsigned short*)d_ws;
  prep_w_all<<<4096, 256, 0, stream>>>(W1_0, W2_0, W1_1, W2_1, Wt);

  fused_mixer<<<16384 / RT, NTH, 0, stream>>>(
      x, Wt, Wt + WSZ, b1_0, b2_0, Wt + 2 * WSZ, Wt + 3 * WSZ, b1_1, b2_1, out);
}

// Round 4
// 285.292 us; speedup vs baseline: 1.3092x; 1.0657x over previous
//
#include <hip/hip_runtime.h>

#define D    2048
#define NB   32
#define BD   64
#define HD   128
#define WSZ  (NB * HD * BD)   // 262144 elems per weight matrix

typedef __attribute__((ext_vector_type(8))) short short8;
typedef __attribute__((ext_vector_type(4))) float floatx4;

static __device__ __forceinline__ unsigned short f2bf(float f) {
  union { float f; unsigned u; } v; v.f = f;
  return (unsigned short)((v.u + 0x7FFFu + ((v.u >> 16) & 1u)) >> 16);
}
static __device__ __forceinline__ float bf2f(unsigned short h) {
  union { unsigned u; float f; } v; v.u = ((unsigned)h) << 16;
  return v.f;
}
static __device__ __forceinline__ float fast_exp2(float x) {
  float r; asm("v_exp_f32 %0, %1" : "=v"(r) : "v"(x)); return r;
}
static __device__ __forceinline__ float fast_rcp(float x) {
  float r; asm("v_rcp_f32 %0, %1" : "=v"(r) : "v"(x)); return r;
}
// sigmoid-form GELU (validated r1/r2: absmax 136 < 586)
static __device__ __forceinline__ float gelu_f(float x) {
  float x2 = x * x;
  float w  = __builtin_fmaf(x2, 0.044715f, 1.0f);
  float e  = fast_exp2(x * w * -2.3022083f);
  return x * fast_rcp(1.0f + e);
}

// per-wave H scratch [16][64], XOR swizzle keeps ushort4/short8 granules intact
static __device__ __forceinline__ int hsw(int row, int col) {
  return row * 64 + (col ^ ((row & 7) << 3));
}
// padded LDS index for 64-short rows -> stride 72 (keeps 8B alignment: 72=8*9)
static __device__ __forceinline__ int pidx(int s) { return s + ((s >> 6) << 3); }

// ---------------------------------------------------------------------------
// Block-major MLP layer. WG = (block n, 512-row chunk), 4 waves x 8 tiles of
// 16 rows. W1[n],W2[n] live in 128 VGPRs per wave (loaded ONCE -> kills the
// round-2 per-tile L2 weight-latency chains). Inner loop: independent
// activation loads, prefetched one tile ahead, ISSUED BEFORE current tile's
// stores (so the in-place bf16 mode needs no restrict and still pipelines).
// ---------------------------------------------------------------------------
template<bool F32IN>
__global__ __launch_bounds__(256, 2) void mlp_layer(
    const float* __restrict__ xf,      // used when F32IN
    unsigned short* yio,               // bf16 input (when !F32IN) AND output; in-place
    const unsigned short* __restrict__ Wt1,  // [n][128][64] bf16 (W1 transposed)
    const unsigned short* __restrict__ Wt2,  // [n][64][128] bf16 (W2 transposed)
    const float* __restrict__ b1,
    const float* __restrict__ b2) {
  __shared__ unsigned short Hs[4][16 * 64];
  const int n     = blockIdx.x >> 5;
  const int chunk = blockIdx.x & 31;
  const int t = threadIdx.x, wv = t >> 6, l = t & 63;
  const int lr = l & 15, q = l >> 4;
  unsigned short* Hp = Hs[wv];

  // ---- weights -> registers (batched, reused for all 8 tiles) ----
  short8 w1r[16], w2r[16];
#pragma unroll
  for (int half = 0; half < 2; ++half)
#pragma unroll
    for (int ot = 0; ot < 4; ++ot)
#pragma unroll
      for (int j = 0; j < 2; ++j)
        w1r[half * 8 + ot * 2 + j] =
            *(const short8*)&Wt1[(n * HD + half * 64 + ot * 16 + lr) * BD + j * 32 + q * 8];
#pragma unroll
  for (int ot = 0; ot < 4; ++ot)
#pragma unroll
    for (int half = 0; half < 2; ++half)
#pragma unroll
      for (int j = 0; j < 2; ++j)
        w2r[ot * 4 + half * 2 + j] =
            *(const short8*)&Wt2[(n * BD + ot * 16 + lr) * HD + half * 64 + j * 32 + q * 8];

  const int rbase = chunk * 512 + wv * 128 + lr;   // + i*16 per tile

  // ---- software pipeline: load tile 0 ----
  float4 uf[2][4];
  short8 xp[2][2];
  if constexpr (F32IN) {
    const float* xr = xf + (size_t)rbase * D + n * BD + q * 8;
    uf[0][0] = *(const float4*)(xr);      uf[0][1] = *(const float4*)(xr + 4);
    uf[0][2] = *(const float4*)(xr + 32); uf[0][3] = *(const float4*)(xr + 36);
  } else {
    const unsigned short* yr = yio + (size_t)rbase * D + n * BD + q * 8;
    xp[0][0] = *(const short8*)(yr); xp[0][1] = *(const short8*)(yr + 32);
  }

  const floatx4 zero = {0.f, 0.f, 0.f, 0.f};
#pragma unroll
  for (int i = 0; i < 8; ++i) {
    const int cur = i & 1, nxt = cur ^ 1;
    short8 xb0, xb1;
    if constexpr (F32IN) {
      short8 t0, t1;
      t0[0] = f2bf(uf[cur][0].x); t0[1] = f2bf(uf[cur][0].y);
      t0[2] = f2bf(uf[cur][0].z); t0[3] = f2bf(uf[cur][0].w);
      t0[4] = f2bf(uf[cur][1].x); t0[5] = f2bf(uf[cur][1].y);
      t0[6] = f2bf(uf[cur][1].z); t0[7] = f2bf(uf[cur][1].w);
      t1[0] = f2bf(uf[cur][2].x); t1[1] = f2bf(uf[cur][2].y);
      t1[2] = f2bf(uf[cur][2].z); t1[3] = f2bf(uf[cur][2].w);
      t1[4] = f2bf(uf[cur][3].x); t1[5] = f2bf(uf[cur][3].y);
      t1[6] = f2bf(uf[cur][3].z); t1[7] = f2bf(uf[cur][3].w);
      xb0 = t0; xb1 = t1;
    } else {
      xb0 = xp[cur][0]; xb1 = xp[cur][1];
    }

    // ---- GEMM1 + gelu + GEMM2 (weights in regs) ----
    floatx4 acc2[4] = {zero, zero, zero, zero};
#pragma unroll
    for (int half = 0; half < 2; ++half) {
      floatx4 acc1[4] = {zero, zero, zero, zero};
#pragma unroll
      for (int ot = 0; ot < 4; ++ot) {
        acc1[ot] = __builtin_amdgcn_mfma_f32_16x16x32_bf16(w1r[half * 8 + ot * 2 + 0], xb0, acc1[ot], 0, 0, 0);
        acc1[ot] = __builtin_amdgcn_mfma_f32_16x16x32_bf16(w1r[half * 8 + ot * 2 + 1], xb1, acc1[ot], 0, 0, 0);
      }
#pragma unroll
      for (int ot = 0; ot < 4; ++ot) {
        const float4 bb = *(const float4*)&b1[n * HD + half * 64 + ot * 16 + q * 4];
        ushort4 hv;
        hv.x = f2bf(gelu_f(acc1[ot][0] + bb.x));
        hv.y = f2bf(gelu_f(acc1[ot][1] + bb.y));
        hv.z = f2bf(gelu_f(acc1[ot][2] + bb.z));
        hv.w = f2bf(gelu_f(acc1[ot][3] + bb.w));
        *(ushort4*)&Hp[hsw(lr, ot * 16 + q * 4)] = hv;
      }
      short8 hb0 = *(const short8*)&Hp[hsw(lr, q * 8)];        // in-wave DS RAW (ordered)
      short8 hb1 = *(const short8*)&Hp[hsw(lr, 32 + q * 8)];
#pragma unroll
      for (int ot = 0; ot < 4; ++ot) {
        acc2[ot] = __builtin_amdgcn_mfma_f32_16x16x32_bf16(w2r[ot * 4 + half * 2 + 0], hb0, acc2[ot], 0, 0, 0);
        acc2[ot] = __builtin_amdgcn_mfma_f32_16x16x32_bf16(w2r[ot * 4 + half * 2 + 1], hb1, acc2[ot], 0, 0, 0);
      }
    }

    // ---- prefetch tile i+1 BEFORE this tile's stores ----
    if (i < 7) {
      const int r2 = rbase + (i + 1) * 16;
      if constexpr (F32IN) {
        const float* xr = xf + (size_t)r2 * D + n * BD + q * 8;
        uf[nxt][0] = *(const float4*)(xr);      uf[nxt][1] = *(const float4*)(xr + 4);
        uf[nxt][2] = *(const float4*)(xr + 32); uf[nxt][3] = *(const float4*)(xr + 36);
      } else {
        const unsigned short* yr = yio + (size_t)r2 * D + n * BD + q * 8;
        xp[nxt][0] = *(const short8*)(yr); xp[nxt][1] = *(const short8*)(yr + 32);
      }
    }

    // ---- bias + store (linear, in-place safe: reads of this tile are done) ----
    unsigned short* yo = yio + (size_t)(rbase + i * 16) * D + n * BD;
#pragma unroll
    for (int ot = 0; ot < 4; ++ot) {
      const float4 bb = *(const float4*)&b2[n * BD + ot * 16 + q * 4];
      ushort4 ov;
      ov.x = f2bf(acc2[ot][0] + bb.x);
      ov.y = f2bf(acc2[ot][1] + bb.y);
      ov.z = f2bf(acc2[ot][2] + bb.z);
      ov.w = f2bf(acc2[ot][3] + bb.w);
      *(ushort4*)&yo[ot * 16 + q * 4] = ov;
    }
  }
}

// ---------------------------------------------------------------------------
// In-place 64x64 transpose of each 2-row (4096-elem) group of Y, via LDS.
// ---------------------------------------------------------------------------
__global__ __launch_bounds__(256) void permute_k(unsigned short* Y) {
  __shared__ unsigned short L[4096 + 64 * 8];
  const int t = threadIdx.x;
  for (int gi = 0; gi < 8; ++gi) {
    unsigned short* Yg = Y + ((size_t)blockIdx.x * 8 + gi) * 4096;
    // coalesced load: 16 consecutive shorts per thread (one 64-row, so the
    // padded destination stays contiguous; stride 72 keeps 8B alignment)
    short8 v0 = *(const short8*)&Yg[t * 16];
    short8 v1 = *(const short8*)&Yg[t * 16 + 8];
    const int pb = pidx(t * 16);
    *(short4*)&L[pb +  0] = *((short4*)&v0);
    *(short4*)&L[pb +  4] = *((short4*)&v0 + 1);
    *(short4*)&L[pb +  8] = *((short4*)&v1);
    *(short4*)&L[pb + 12] = *((short4*)&v1 + 1);
    __syncthreads();
    // gather transposed: out p = t*16+k  ->  src s = (p&63)*64 + (p>>6)
    unsigned short g[16];
    const int j = t >> 2, i0 = (t & 3) * 16;
#pragma unroll
    for (int k = 0; k < 16; ++k) g[k] = L[pidx((i0 + k) * 64 + j)];
    short8 o0, o1;
#pragma unroll
    for (int k = 0; k < 8; ++k) { o0[k] = (short)g[k]; o1[k] = (short)g[8 + k]; }
    __syncthreads();                       // LDS reusable next iteration
    *(short8*)&Yg[t * 16]     = o0;        // in-place write-back (same WG)
    *(short8*)&Yg[t * 16 + 8] = o1;
  }
}

// ---------------------------------------------------------------------------
// Final: un-permute (same 64x64 group transpose) + bf16 -> f32 store to out.
// ---------------------------------------------------------------------------
__global__ __launch_bounds__(256) void unpermute_k(const unsigned short* __restrict__ Y,
                                                   float* __restrict__ out) {
  __shared__ unsigned short L[4096 + 64 * 8];
  const int t = threadIdx.x;
  for (int gi = 0; gi < 8; ++gi) {
    const size_t gbase = ((size_t)blockIdx.x * 8 + gi) * 4096;
    const unsigned short* Yg = Y + gbase;
    short8 v0 = *(const short8*)&Yg[t * 16];
    short8 v1 = *(const short8*)&Yg[t * 16 + 8];
    const int pb = pidx(t * 16);
    *(short4*)&L[pb +  0] = *((short4*)&v0);
    *(short4*)&L[pb +  4] = *((short4*)&v0 + 1);
    *(short4*)&L[pb +  8] = *((short4*)&v1);
    *(short4*)&L[pb + 12] = *((short4*)&v1 + 1);
    __syncthreads();
    // out flat o = t*16+k: a=o>>11, c=o&2047; src s = (c&63)*64 + a*32 + (c>>6)
    const int o0f = t * 16;
    const int a = o0f >> 11, c0 = o0f & 2047;
    const int s0 = (c0 & 63) * 64 + (a << 5) + (c0 >> 6);
    float f[16];
#pragma unroll
    for (int k = 0; k < 16; ++k) f[k] = bf2f(L[pidx(s0 + k * 64)]);
    __syncthreads();
    float* op = out + gbase + o0f;
#pragma unroll
    for (int k = 0; k < 4; ++k) {
      float4 fv; fv.x = f[4 * k]; fv.y = f[4 * k + 1]; fv.z = f[4 * k + 2]; fv.w = f[4 * k + 3];
      *(float4*)(op + 4 * k) = fv;
    }
  }
}

// W [n][R][C] f32 -> Wt [n][C][R] bf16, all four matrices in one launch
__global__ void prep_w_all(const float* __restrict__ W1_0, const float* __restrict__ W2_0,
                           const float* __restrict__ W1_1, const float* __restrict__ W2_1,
                           unsigned short* __restrict__ dst) {
  const int seg = blockIdx.x >> 10;
  const int id  = ((blockIdx.x & 1023) << 8) | threadIdx.x;
  const float* W; int R;
  if      (seg == 0) { W = W1_0; R = BD; }
  else if (seg == 1) { W = W2_0; R = HD; }
  else if (seg == 2) { W = W1_1; R = BD; }
  else               { W = W2_1; R = HD; }
  const int C   = (R == BD) ? HD : BD;
  const int n   = id >> 13;
  const int rem = id & 8191;
  const int c   = rem / R;
  const int r   = rem - c * R;
  dst[seg * WSZ + id] = f2bf(W[(n * R + r) * C + c]);
}

extern "C" void kernel_launch(void* const* d_in, const int* in_sizes, int n_in,
                              void* d_out, int out_size, void* d_ws, size_t ws_size,
                              hipStream_t stream) {
  const float* x    = (const float*)d_in[0];
  const float* W1_0 = (const float*)d_in[1];
  const float* b1_0 = (const float*)d_in[2];
  const float* W2_0 = (const float*)d_in[3];
  const float* b2_0 = (const float*)d_in[4];
  const float* W1_1 = (const float*)d_in[5];
  const float* b1_1 = (const float*)d_in[6];
  const float* W2_1 = (const float*)d_in[7];
  const float* b2_1 = (const float*)d_in[8];
  float* out = (float*)d_out;

  // ws layout: [Wt: 4 x 512KB = 2MB][Y: 16384*2048 bf16 = 64MB]  (~66MB total)
  unsigned short* Wt = (unsigned short*)d_ws;
  unsigned short* Y  = Wt + 4 * WSZ;

  prep_w_all<<<4096, 256, 0, stream>>>(W1_0, W2_0, W1_1, W2_1, Wt);
  mlp_layer<true ><<<1024, 256, 0, stream>>>(x, Y, Wt, Wt + WSZ, b1_0, b2_0);
  permute_k<<<1024, 256, 0, stream>>>(Y);
  mlp_layer<false><<<1024, 256, 0, stream>>>(nullptr, Y, Wt + 2 * WSZ, Wt + 3 * WSZ, b1_1, b2_1);
  unpermute_k<<<1024, 256, 0, stream>>>(Y, out);
}

// Round 6
// 183.330 us; speedup vs baseline: 2.0373x; 1.5562x over previous
//
#include <hip/hip_runtime.h>

#define D    2048
#define NB   32
#define BD   64
#define HD   128
#define WSZ  (NB * HD * BD)   // 262144 elems per weight matrix

typedef __attribute__((ext_vector_type(8))) short short8;
typedef __attribute__((ext_vector_type(4))) float floatx4;

static __device__ __forceinline__ unsigned short f2bf(float f) {
  union { float f; unsigned u; } v; v.f = f;
  return (unsigned short)((v.u + 0x7FFFu + ((v.u >> 16) & 1u)) >> 16);
}
static __device__ __forceinline__ float bf2f(unsigned short h) {
  union { unsigned u; float f; } v; v.u = ((unsigned)h) << 16;
  return v.f;
}
static __device__ __forceinline__ float fast_exp2(float x) {
  float r; asm("v_exp_f32 %0, %1" : "=v"(r) : "v"(x)); return r;
}
static __device__ __forceinline__ float fast_rcp(float x) {
  float r; asm("v_rcp_f32 %0, %1" : "=v"(r) : "v"(x)); return r;
}
// sigmoid-form GELU (validated r1/r2/r4: absmax 136 < 586)
static __device__ __forceinline__ float gelu_f(float x) {
  float x2 = x * x;
  float w  = __builtin_fmaf(x2, 0.044715f, 1.0f);
  float e  = fast_exp2(x * w * -2.3022083f);
  return x * fast_rcp(1.0f + e);
}

// per-wave H scratch [16][64]: XOR swizzle keeps 8B/16B granules intact
static __device__ __forceinline__ int hsw(int row, int col) {
  return row * 64 + (col ^ ((row & 7) << 3));
}
// padded LDS index for the permute kernels (stride 72 keeps 8B alignment)
static __device__ __forceinline__ int pidx(int s) { return s + ((s >> 6) << 3); }

// ---------------------------------------------------------------------------
// Block-major MLP layer (round-6 = round-5 structure with PROVEN f2bf
// packing; round-5's v_cvt_pk_bf16_f32 inline asm produced NaNs):
//  - W1[n],W2[n] in WG-shared LDS (32KB), staged once; pre-swizzled by prep so
//    fragment ds_read_b128 is ~2-way-conflict (free per m136). Frees ~128
//    regs/wave vs round-4's register/AGPR-resident weights -> 3 waves/SIMD.
//  - biases folded into accumulator init (hoisted per WG; they are zeros).
// ---------------------------------------------------------------------------
template<bool F32IN>
__global__ __launch_bounds__(256, 3) void mlp_layer(
    const float* __restrict__ xf,      // used when F32IN
    unsigned short* yio,               // bf16 input (when !F32IN) AND output
    const unsigned short* __restrict__ Wt1,  // [n][128][64] bf16, pre-swizzled
    const unsigned short* __restrict__ Wt2,  // [n][64][128] bf16, pre-swizzled
    const float* __restrict__ b1,
    const float* __restrict__ b2) {
  __shared__ unsigned short Wlds[16384];     // 32KB: [0..8191]=W1t, [8192..]=W2t
  __shared__ unsigned short Hs[4][16 * 64];  // 8KB H scratch, per wave
  const int n     = blockIdx.x >> 5;
  const int chunk = blockIdx.x & 31;
  const int t = threadIdx.x, wv = t >> 6, l = t & 63;
  const int lr = l & 15, q = l >> 4;
  unsigned short* Hp = Hs[wv];

  // ---- stage both weight matrices into LDS (linear copy of swizzled image) ----
  {
    const unsigned short* s1 = Wt1 + n * 8192;
    const unsigned short* s2 = Wt2 + n * 8192;
#pragma unroll
    for (int i = 0; i < 4; ++i) {
      const int e = (i * 256 + t) * 8;
      *(short8*)&Wlds[e]        = *(const short8*)&s1[e];
      *(short8*)&Wlds[8192 + e] = *(const short8*)&s2[e];
    }
  }

  // ---- biases -> accumulator-init fragments (loaded once per WG) ----
  floatx4 bias1v[8], bias2v[4];
#pragma unroll
  for (int hf = 0; hf < 2; ++hf)
#pragma unroll
    for (int ot = 0; ot < 4; ++ot) {
      const float4 bb = *(const float4*)&b1[n * HD + hf * 64 + ot * 16 + q * 4];
      floatx4 v; v[0] = bb.x; v[1] = bb.y; v[2] = bb.z; v[3] = bb.w;
      bias1v[hf * 4 + ot] = v;
    }
#pragma unroll
  for (int ot = 0; ot < 4; ++ot) {
    const float4 bb = *(const float4*)&b2[n * BD + ot * 16 + q * 4];
    floatx4 v; v[0] = bb.x; v[1] = bb.y; v[2] = bb.z; v[3] = bb.w;
    bias2v[ot] = v;
  }

  const int rbase = chunk * 512 + wv * 128 + lr;   // + i*16 per tile

  // ---- software pipeline: load tile 0 activations ----
  float4 uf[2][4];
  short8 xp[2][2];
  if constexpr (F32IN) {
    const float* xr = xf + (size_t)rbase * D + n * BD + q * 8;
    uf[0][0] = *(const float4*)(xr);      uf[0][1] = *(const float4*)(xr + 4);
    uf[0][2] = *(const float4*)(xr + 32); uf[0][3] = *(const float4*)(xr + 36);
  } else {
    const unsigned short* yr = yio + (size_t)rbase * D + n * BD + q * 8;
    xp[0][0] = *(const short8*)(yr); xp[0][1] = *(const short8*)(yr + 32);
  }

  __syncthreads();   // weights staged

#pragma unroll
  for (int i = 0; i < 8; ++i) {
    const int cur = i & 1, nxt = cur ^ 1;
    short8 xb0, xb1;
    if constexpr (F32IN) {
      short8 t0, t1;
      t0[0] = f2bf(uf[cur][0].x); t0[1] = f2bf(uf[cur][0].y);
      t0[2] = f2bf(uf[cur][0].z); t0[3] = f2bf(uf[cur][0].w);
      t0[4] = f2bf(uf[cur][1].x); t0[5] = f2bf(uf[cur][1].y);
      t0[6] = f2bf(uf[cur][1].z); t0[7] = f2bf(uf[cur][1].w);
      t1[0] = f2bf(uf[cur][2].x); t1[1] = f2bf(uf[cur][2].y);
      t1[2] = f2bf(uf[cur][2].z); t1[3] = f2bf(uf[cur][2].w);
      t1[4] = f2bf(uf[cur][3].x); t1[5] = f2bf(uf[cur][3].y);
      t1[6] = f2bf(uf[cur][3].z); t1[7] = f2bf(uf[cur][3].w);
      xb0 = t0; xb1 = t1;
    } else {
      xb0 = xp[cur][0]; xb1 = xp[cur][1];
    }

    floatx4 acc2[4] = {bias2v[0], bias2v[1], bias2v[2], bias2v[3]};
#pragma unroll
    for (int hf = 0; hf < 2; ++hf) {
      floatx4 acc1[4] = {bias1v[hf * 4 + 0], bias1v[hf * 4 + 1],
                         bias1v[hf * 4 + 2], bias1v[hf * 4 + 3]};
      // GEMM1: A-frags from LDS (swizzled; k-cols spread across bank groups)
#pragma unroll
      for (int ot = 0; ot < 4; ++ot) {
        const int row = hf * 64 + ot * 16 + lr;
        const int sw  = (lr & 7) << 3;
        short8 a0 = *(const short8*)&Wlds[row * 64 + ((q * 8)      ^ sw)];
        short8 a1 = *(const short8*)&Wlds[row * 64 + ((32 + q * 8) ^ sw)];
        acc1[ot] = __builtin_amdgcn_mfma_f32_16x16x32_bf16(a0, xb0, acc1[ot], 0, 0, 0);
        acc1[ot] = __builtin_amdgcn_mfma_f32_16x16x32_bf16(a1, xb1, acc1[ot], 0, 0, 0);
      }
      // gelu + bf16 convert -> H LDS
#pragma unroll
      for (int ot = 0; ot < 4; ++ot) {
        ushort4 hv;
        hv.x = f2bf(gelu_f(acc1[ot][0]));
        hv.y = f2bf(gelu_f(acc1[ot][1]));
        hv.z = f2bf(gelu_f(acc1[ot][2]));
        hv.w = f2bf(gelu_f(acc1[ot][3]));
        *(ushort4*)&Hp[hsw(lr, ot * 16 + q * 4)] = hv;
      }
      short8 hb0 = *(const short8*)&Hp[hsw(lr, q * 8)];        // in-wave DS RAW
      short8 hb1 = *(const short8*)&Hp[hsw(lr, 32 + q * 8)];
      // GEMM2: A-frags from LDS
#pragma unroll
      for (int ot = 0; ot < 4; ++ot) {
        const int row = ot * 16 + lr;
        const int sw  = (lr & 7) << 3;
        short8 c0 = *(const short8*)&Wlds[8192 + row * 128 + ((hf * 64 + q * 8)      ^ sw)];
        short8 c1 = *(const short8*)&Wlds[8192 + row * 128 + ((hf * 64 + 32 + q * 8) ^ sw)];
        acc2[ot] = __builtin_amdgcn_mfma_f32_16x16x32_bf16(c0, hb0, acc2[ot], 0, 0, 0);
        acc2[ot] = __builtin_amdgcn_mfma_f32_16x16x32_bf16(c1, hb1, acc2[ot], 0, 0, 0);
      }
    }

    // ---- prefetch tile i+1 BEFORE this tile's stores ----
    if (i < 7) {
      const int r2 = rbase + (i + 1) * 16;
      if constexpr (F32IN) {
        const float* xr = xf + (size_t)r2 * D + n * BD + q * 8;
        uf[nxt][0] = *(const float4*)(xr);      uf[nxt][1] = *(const float4*)(xr + 4);
        uf[nxt][2] = *(const float4*)(xr + 32); uf[nxt][3] = *(const float4*)(xr + 36);
      } else {
        const unsigned short* yr = yio + (size_t)r2 * D + n * BD + q * 8;
        xp[nxt][0] = *(const short8*)(yr); xp[nxt][1] = *(const short8*)(yr + 32);
      }
    }

    // ---- store (bias already in acc init) ----
    unsigned short* yo = yio + (size_t)(rbase + i * 16) * D + n * BD;
#pragma unroll
    for (int ot = 0; ot < 4; ++ot) {
      ushort4 ov;
      ov.x = f2bf(acc2[ot][0]);
      ov.y = f2bf(acc2[ot][1]);
      ov.z = f2bf(acc2[ot][2]);
      ov.w = f2bf(acc2[ot][3]);
      *(ushort4*)&yo[ot * 16 + q * 4] = ov;
    }
  }
}

// ---------------------------------------------------------------------------
// In-place 64x64 transpose of each 2-row (4096-elem) group of Y, via LDS.
// ---------------------------------------------------------------------------
__global__ __launch_bounds__(256) void permute_k(unsigned short* Y) {
  __shared__ unsigned short L[4096 + 64 * 8];
  const int t = threadIdx.x;
  for (int gi = 0; gi < 8; ++gi) {
    unsigned short* Yg = Y + ((size_t)blockIdx.x * 8 + gi) * 4096;
    short8 v0 = *(const short8*)&Yg[t * 16];
    short8 v1 = *(const short8*)&Yg[t * 16 + 8];
    const int pb = pidx(t * 16);
    *(short4*)&L[pb +  0] = *((short4*)&v0);
    *(short4*)&L[pb +  4] = *((short4*)&v0 + 1);
    *(short4*)&L[pb +  8] = *((short4*)&v1);
    *(short4*)&L[pb + 12] = *((short4*)&v1 + 1);
    __syncthreads();
    unsigned short g[16];
    const int j = t >> 2, i0 = (t & 3) * 16;
#pragma unroll
    for (int k = 0; k < 16; ++k) g[k] = L[pidx((i0 + k) * 64 + j)];
    short8 o0, o1;
#pragma unroll
    for (int k = 0; k < 8; ++k) { o0[k] = (short)g[k]; o1[k] = (short)g[8 + k]; }
    __syncthreads();
    *(short8*)&Yg[t * 16]     = o0;
    *(short8*)&Yg[t * 16 + 8] = o1;
  }
}

// ---------------------------------------------------------------------------
// Final: un-permute (same 64x64 group transpose) + bf16 -> f32 store to out.
// ---------------------------------------------------------------------------
__global__ __launch_bounds__(256) void unpermute_k(const unsigned short* __restrict__ Y,
                                                   float* __restrict__ out) {
  __shared__ unsigned short L[4096 + 64 * 8];
  const int t = threadIdx.x;
  for (int gi = 0; gi < 8; ++gi) {
    const size_t gbase = ((size_t)blockIdx.x * 8 + gi) * 4096;
    const unsigned short* Yg = Y + gbase;
    short8 v0 = *(const short8*)&Yg[t * 16];
    short8 v1 = *(const short8*)&Yg[t * 16 + 8];
    const int pb = pidx(t * 16);
    *(short4*)&L[pb +  0] = *((short4*)&v0);
    *(short4*)&L[pb +  4] = *((short4*)&v0 + 1);
    *(short4*)&L[pb +  8] = *((short4*)&v1);
    *(short4*)&L[pb + 12] = *((short4*)&v1 + 1);
    __syncthreads();
    const int o0f = t * 16;
    const int a = o0f >> 11, c0 = o0f & 2047;
    const int s0 = (c0 & 63) * 64 + (a << 5) + (c0 >> 6);
    float f[16];
#pragma unroll
    for (int k = 0; k < 16; ++k) f[k] = bf2f(L[pidx(s0 + k * 64)]);
    __syncthreads();
    float* op = out + gbase + o0f;
#pragma unroll
    for (int k = 0; k < 4; ++k) {
      float4 fv; fv.x = f[4 * k]; fv.y = f[4 * k + 1]; fv.z = f[4 * k + 2]; fv.w = f[4 * k + 3];
      *(float4*)(op + 4 * k) = fv;
    }
  }
}

// W [n][R][C] f32 -> Wt [n][C][R] bf16, transposed AND XOR-swizzled
// (dst col r ^= (c&7)<<3) so mlp_layer's LDS copy is linear and its
// ds_read_b128 fragment reads land ~2-way-conflict-free.
__global__ void prep_w_all(const float* __restrict__ W1_0, const float* __restrict__ W2_0,
                           const float* __restrict__ W1_1, const float* __restrict__ W2_1,
                           unsigned short* __restrict__ dst) {
  const int seg = blockIdx.x >> 10;
  const int id  = ((blockIdx.x & 1023) << 8) | threadIdx.x;
  const float* W; int R;
  if      (seg == 0) { W = W1_0; R = BD; }
  else if (seg == 1) { W = W2_0; R = HD; }
  else if (seg == 2) { W = W1_1; R = BD; }
  else               { W = W2_1; R = HD; }
  const int C   = (R == BD) ? HD : BD;
  const int n   = id >> 13;
  const int rem = id & 8191;
  const int c   = rem / R;          // dst row (out-feature), stride R
  const int r   = rem - c * R;      // dst col (k index)
  dst[seg * WSZ + n * 8192 + c * R + (r ^ ((c & 7) << 3))] =
      f2bf(W[(n * R + r) * C + c]);
}

extern "C" void kernel_launch(void* const* d_in, const int* in_sizes, int n_in,
                              void* d_out, int out_size, void* d_ws, size_t ws_size,
                              hipStream_t stream) {
  const float* x    = (const float*)d_in[0];
  const float* W1_0 = (const float*)d_in[1];
  const float* b1_0 = (const float*)d_in[2];
  const float* W2_0 = (const float*)d_in[3];
  const float* b2_0 = (const float*)d_in[4];
  const float* W1_1 = (const float*)d_in[5];
  const float* b1_1 = (const float*)d_in[6];
  const float* W2_1 = (const float*)d_in[7];
  const float* b2_1 = (const float*)d_in[8];
  float* out = (float*)d_out;

  // ws layout: [Wt: 4 x 512KB = 2MB][Y: 16384*2048 bf16 = 64MB]
  unsigned short* Wt = (unsigned short*)d_ws;
  unsigned short* Y  = Wt + 4 * WSZ;

  prep_w_all<<<4096, 256, 0, stream>>>(W1_0, W2_0, W1_1, W2_1, Wt);
  mlp_layer<true ><<<1024, 256, 0, stream>>>(x, Y, Wt, Wt + WSZ, b1_0, b2_0);
  permute_k<<<1024, 256, 0, stream>>>(Y);
  mlp_layer<false><<<1024, 256, 0, stream>>>(nullptr, Y, Wt + 2 * WSZ, Wt + 3 * WSZ, b1_1, b2_1);
  unpermute_k<<<1024, 256, 0, stream>>>(Y, out);
}

// Round 7
// 180.987 us; speedup vs baseline: 2.0636x; 1.0129x over previous
//
#include <hip/hip_runtime.h>
#include <hip/hip_bf16.h>

#define D    2048
#define NB   32
#define BD   64
#define HD   128
#define WSZ  (NB * HD * BD)   // 262144 elems per weight matrix

typedef __attribute__((ext_vector_type(8))) short short8;
typedef __attribute__((ext_vector_type(4))) float floatx4;

static __device__ __forceinline__ unsigned short f2bf(float f) {
  union { float f; unsigned u; } v; v.f = f;
  return (unsigned short)((v.u + 0x7FFFu + ((v.u >> 16) & 1u)) >> 16);
}
static __device__ __forceinline__ float bf2f(unsigned short h) {
  union { unsigned u; float f; } v; v.u = ((unsigned)h) << 16;
  return v.f;
}
// packed f32x2 -> bf16x2 via official HIP API (round-5 inline asm was broken)
static __device__ __forceinline__ unsigned pk2(float a, float b) {
  float2 t; t.x = a; t.y = b;
  __hip_bfloat162 h = __float22bfloat162_rn(t);
  unsigned u; __builtin_memcpy(&u, &h, 4);
  return u;
}
static __device__ __forceinline__ float fast_exp2(float x) {
  float r; asm("v_exp_f32 %0, %1" : "=v"(r) : "v"(x)); return r;
}
static __device__ __forceinline__ float fast_rcp(float x) {
  float r; asm("v_rcp_f32 %0, %1" : "=v"(r) : "v"(x)); return r;
}
// sigmoid-form GELU (validated r1/r2/r4/r6: absmax 136 < 586)
static __device__ __forceinline__ float gelu_f(float x) {
  float x2 = x * x;
  float w  = __builtin_fmaf(x2, 0.044715f, 1.0f);
  float e  = fast_exp2(x * w * -2.3022083f);
  return x * fast_rcp(1.0f + e);
}

// padded LDS index for the permute kernels (stride 72 keeps 8B alignment)
static __device__ __forceinline__ int pidx(int s) { return s + ((s >> 6) << 3); }

// ---------------------------------------------------------------------------
// Block-major MLP layer, round-7 structure:
//  - H NEVER touches LDS: W2's k-axis is pre-permuted (prep) so the GEMM1
//    accumulator (C-layout: lane(lr,q) holds features (j>>2)*16+q*4+(j&3))
//    is a valid GEMM2 B-fragment after gelu+pk2 pack. MFMA k-permutation
//    applied to both operands is identity on the result.
//  - LDS = exactly 32KB weights -> 512-thread WGs, T=4 tiles/wave, grid 1024.
//  - DS ops/tile: 44 -> 32 (weight frags only); both H RAW chains deleted.
// ---------------------------------------------------------------------------
template<bool F32IN>
__global__ __launch_bounds__(512, 4) void mlp_layer(
    const float* __restrict__ xf,      // used when F32IN
    unsigned short* yio,               // bf16 input (when !F32IN) AND output
    const unsigned short* __restrict__ Wt1,  // [n][128][64] bf16, swizzled
    const unsigned short* __restrict__ Wt2,  // [n][64][128] bf16, slot-permuted+swizzled
    const float* __restrict__ b1,
    const float* __restrict__ b2) {
  __shared__ unsigned short Wlds[16384];     // 32KB: [0..8191]=W1t, [8192..]=W2t
  const int n     = blockIdx.x >> 5;
  const int chunk = blockIdx.x & 31;
  const int t = threadIdx.x, wv = t >> 6, l = t & 63;
  const int lr = l & 15, q = l >> 4;
  const int sw = (lr & 7) << 3;

  // ---- stage both weight matrices into LDS (linear copy of prepped image) ----
  {
    const unsigned short* s1 = Wt1 + n * 8192;
    const unsigned short* s2 = Wt2 + n * 8192;
#pragma unroll
    for (int i = 0; i < 2; ++i) {
      const int e = (i * 512 + t) * 8;
      *(short8*)&Wlds[e]        = *(const short8*)&s1[e];
      *(short8*)&Wlds[8192 + e] = *(const short8*)&s2[e];
    }
  }

  // ---- biases -> accumulator-init fragments (loaded once per WG) ----
  floatx4 bias1v[8], bias2v[4];
#pragma unroll
  for (int hf = 0; hf < 2; ++hf)
#pragma unroll
    for (int ot = 0; ot < 4; ++ot) {
      const float4 bb = *(const float4*)&b1[n * HD + hf * 64 + ot * 16 + q * 4];
      floatx4 v; v[0] = bb.x; v[1] = bb.y; v[2] = bb.z; v[3] = bb.w;
      bias1v[hf * 4 + ot] = v;
    }
#pragma unroll
  for (int ot = 0; ot < 4; ++ot) {
    const float4 bb = *(const float4*)&b2[n * BD + ot * 16 + q * 4];
    floatx4 v; v[0] = bb.x; v[1] = bb.y; v[2] = bb.z; v[3] = bb.w;
    bias2v[ot] = v;
  }

  const int rbase = chunk * 512 + wv * 64 + lr;   // + i*16 per tile, 4 tiles

  // ---- software pipeline: load tile 0 activations ----
  float4 uf[2][4];
  short8 xp[2][2];
  if constexpr (F32IN) {
    const float* xr = xf + (size_t)rbase * D + n * BD + q * 8;
    uf[0][0] = *(const float4*)(xr);      uf[0][1] = *(const float4*)(xr + 4);
    uf[0][2] = *(const float4*)(xr + 32); uf[0][3] = *(const float4*)(xr + 36);
  } else {
    const unsigned short* yr = yio + (size_t)rbase * D + n * BD + q * 8;
    xp[0][0] = *(const short8*)(yr); xp[0][1] = *(const short8*)(yr + 32);
  }

  __syncthreads();   // weights staged

#pragma unroll
  for (int i = 0; i < 4; ++i) {
    const int cur = i & 1, nxt = cur ^ 1;
    short8 xb0, xb1;
    if constexpr (F32IN) {
      union { unsigned u[4]; short8 s; } c0, c1;
      c0.u[0] = pk2(uf[cur][0].x, uf[cur][0].y);
      c0.u[1] = pk2(uf[cur][0].z, uf[cur][0].w);
      c0.u[2] = pk2(uf[cur][1].x, uf[cur][1].y);
      c0.u[3] = pk2(uf[cur][1].z, uf[cur][1].w);
      c1.u[0] = pk2(uf[cur][2].x, uf[cur][2].y);
      c1.u[1] = pk2(uf[cur][2].z, uf[cur][2].w);
      c1.u[2] = pk2(uf[cur][3].x, uf[cur][3].y);
      c1.u[3] = pk2(uf[cur][3].z, uf[cur][3].w);
      xb0 = c0.s; xb1 = c1.s;
    } else {
      xb0 = xp[cur][0]; xb1 = xp[cur][1];
    }

    floatx4 acc2[4] = {bias2v[0], bias2v[1], bias2v[2], bias2v[3]};
#pragma unroll
    for (int hf = 0; hf < 2; ++hf) {
      floatx4 acc1[4] = {bias1v[hf * 4 + 0], bias1v[hf * 4 + 1],
                         bias1v[hf * 4 + 2], bias1v[hf * 4 + 3]};
      // GEMM1: A-frags from LDS (swizzled)
#pragma unroll
      for (int ot = 0; ot < 4; ++ot) {
        const int row = hf * 64 + ot * 16 + lr;
        short8 a0 = *(const short8*)&Wlds[row * 64 + ((q * 8)      ^ sw)];
        short8 a1 = *(const short8*)&Wlds[row * 64 + ((32 + q * 8) ^ sw)];
        acc1[ot] = __builtin_amdgcn_mfma_f32_16x16x32_bf16(a0, xb0, acc1[ot], 0, 0, 0);
        acc1[ot] = __builtin_amdgcn_mfma_f32_16x16x32_bf16(a1, xb1, acc1[ot], 0, 0, 0);
      }
      // gelu + pack acc1 DIRECTLY into GEMM2 B-frags (zero-DS H)
      union { unsigned u[4]; short8 s; } hb0, hb1;
      hb0.u[0] = pk2(gelu_f(acc1[0][0]), gelu_f(acc1[0][1]));
      hb0.u[1] = pk2(gelu_f(acc1[0][2]), gelu_f(acc1[0][3]));
      hb0.u[2] = pk2(gelu_f(acc1[1][0]), gelu_f(acc1[1][1]));
      hb0.u[3] = pk2(gelu_f(acc1[1][2]), gelu_f(acc1[1][3]));
      hb1.u[0] = pk2(gelu_f(acc1[2][0]), gelu_f(acc1[2][1]));
      hb1.u[1] = pk2(gelu_f(acc1[2][2]), gelu_f(acc1[2][3]));
      hb1.u[2] = pk2(gelu_f(acc1[3][0]), gelu_f(acc1[3][1]));
      hb1.u[3] = pk2(gelu_f(acc1[3][2]), gelu_f(acc1[3][3]));
      // GEMM2: A-frags from LDS (slot-permuted to match hb layout)
#pragma unroll
      for (int ot = 0; ot < 4; ++ot) {
        const int row = ot * 16 + lr;
        short8 w0 = *(const short8*)&Wlds[8192 + row * 128 + ((hf * 64 + q * 8)      ^ sw)];
        short8 w1 = *(const short8*)&Wlds[8192 + row * 128 + ((hf * 64 + 32 + q * 8) ^ sw)];
        acc2[ot] = __builtin_amdgcn_mfma_f32_16x16x32_bf16(w0, hb0.s, acc2[ot], 0, 0, 0);
        acc2[ot] = __builtin_amdgcn_mfma_f32_16x16x32_bf16(w1, hb1.s, acc2[ot], 0, 0, 0);
      }
    }

    // ---- prefetch tile i+1 BEFORE this tile's stores ----
    if (i < 3) {
      const int r2 = rbase + (i + 1) * 16;
      if constexpr (F32IN) {
        const float* xr = xf + (size_t)r2 * D + n * BD + q * 8;
        uf[nxt][0] = *(const float4*)(xr);      uf[nxt][1] = *(const float4*)(xr + 4);
        uf[nxt][2] = *(const float4*)(xr + 32); uf[nxt][3] = *(const float4*)(xr + 36);
      } else {
        const unsigned short* yr = yio + (size_t)r2 * D + n * BD + q * 8;
        xp[nxt][0] = *(const short8*)(yr); xp[nxt][1] = *(const short8*)(yr + 32);
      }
    }

    // ---- packed store (bias already in acc init) ----
    unsigned short* yo = yio + (size_t)(rbase + i * 16) * D + n * BD;
#pragma unroll
    for (int ot = 0; ot < 4; ++ot) {
      uint2 ov;
      ov.x = pk2(acc2[ot][0], acc2[ot][1]);
      ov.y = pk2(acc2[ot][2], acc2[ot][3]);
      *(uint2*)&yo[ot * 16 + q * 4] = ov;
    }
  }
}

// ---------------------------------------------------------------------------
// In-place 64x64 transpose of each 2-row (4096-elem) group of Y, via LDS.
// ---------------------------------------------------------------------------
__global__ __launch_bounds__(256) void permute_k(unsigned short* Y) {
  __shared__ unsigned short L[4096 + 64 * 8];
  const int t = threadIdx.x;
  for (int gi = 0; gi < 8; ++gi) {
    unsigned short* Yg = Y + ((size_t)blockIdx.x * 8 + gi) * 4096;
    short8 v0 = *(const short8*)&Yg[t * 16];
    short8 v1 = *(const short8*)&Yg[t * 16 + 8];
    const int pb = pidx(t * 16);
    *(short4*)&L[pb +  0] = *((short4*)&v0);
    *(short4*)&L[pb +  4] = *((short4*)&v0 + 1);
    *(short4*)&L[pb +  8] = *((short4*)&v1);
    *(short4*)&L[pb + 12] = *((short4*)&v1 + 1);
    __syncthreads();
    unsigned short g[16];
    const int j = t >> 2, i0 = (t & 3) * 16;
#pragma unroll
    for (int k = 0; k < 16; ++k) g[k] = L[pidx((i0 + k) * 64 + j)];
    short8 o0, o1;
#pragma unroll
    for (int k = 0; k < 8; ++k) { o0[k] = (short)g[k]; o1[k] = (short)g[8 + k]; }
    __syncthreads();
    *(short8*)&Yg[t * 16]     = o0;
    *(short8*)&Yg[t * 16 + 8] = o1;
  }
}

// ---------------------------------------------------------------------------
// Final: un-permute (same 64x64 group transpose) + bf16 -> f32 store to out.
// ---------------------------------------------------------------------------
__global__ __launch_bounds__(256) void unpermute_k(const unsigned short* __restrict__ Y,
                                                   float* __restrict__ out) {
  __shared__ unsigned short L[4096 + 64 * 8];
  const int t = threadIdx.x;
  for (int gi = 0; gi < 8; ++gi) {
    const size_t gbase = ((size_t)blockIdx.x * 8 + gi) * 4096;
    const unsigned short* Yg = Y + gbase;
    short8 v0 = *(const short8*)&Yg[t * 16];
    short8 v1 = *(const short8*)&Yg[t * 16 + 8];
    const int pb = pidx(t * 16);
    *(short4*)&L[pb +  0] = *((short4*)&v0);
    *(short4*)&L[pb +  4] = *((short4*)&v0 + 1);
    *(short4*)&L[pb +  8] = *((short4*)&v1);
    *(short4*)&L[pb + 12] = *((short4*)&v1 + 1);
    __syncthreads();
    const int o0f = t * 16;
    const int a = o0f >> 11, c0 = o0f & 2047;
    const int s0 = (c0 & 63) * 64 + (a << 5) + (c0 >> 6);
    float f[16];
#pragma unroll
    for (int k = 0; k < 16; ++k) f[k] = bf2f(L[pidx(s0 + k * 64)]);
    __syncthreads();
    float* op = out + gbase + o0f;
#pragma unroll
    for (int k = 0; k < 4; ++k) {
      float4 fv; fv.x = f[4 * k]; fv.y = f[4 * k + 1]; fv.z = f[4 * k + 2]; fv.w = f[4 * k + 3];
      *(float4*)(op + 4 * k) = fv;
    }
  }
}

// W [n][R][C] f32 -> Wt [n][C][R] bf16, transposed + XOR-swizzled.
// W2 (odd segs) additionally gets the k-axis SLOT PERMUTATION so GEMM1's
// C-layout accumulator is directly a GEMM2 B-fragment:
//   slot q*8+j  holds  k-feature (j>>2)*16 + q*4 + (j&3)   (per 32-wide step)
__global__ void prep_w_all(const float* __restrict__ W1_0, const float* __restrict__ W2_0,
                           const float* __restrict__ W1_1, const float* __restrict__ W2_1,
                           unsigned short* __restrict__ dst) {
  const int seg = blockIdx.x >> 10;
  const int id  = ((blockIdx.x & 1023) << 8) | threadIdx.x;
  const float* W; int R;
  if      (seg == 0) { W = W1_0; R = BD; }
  else if (seg == 1) { W = W2_0; R = HD; }
  else if (seg == 2) { W = W1_1; R = BD; }
  else               { W = W2_1; R = HD; }
  const int C   = (R == BD) ? HD : BD;
  const int n   = id >> 13;
  const int rem = id & 8191;
  const int c   = rem / R;          // dst row (out-feature)
  const int r   = rem - c * R;      // dst col (k index)
  const unsigned short val = f2bf(W[(n * R + r) * C + c]);
  if (seg & 1) {
    // W2: k-feature r -> slot (bijective), then bank swizzle
    const int hf  = r >> 6, st = (r >> 5) & 1, blk = (r >> 4) & 1;
    const int qq  = (r & 15) >> 2, e = r & 3;
    const int slot = hf * 64 + st * 32 + qq * 8 + blk * 4 + e;
    dst[seg * WSZ + n * 8192 + c * HD + (slot ^ ((c & 7) << 3))] = val;
  } else {
    dst[seg * WSZ + n * 8192 + c * BD + (r ^ ((c & 7) << 3))] = val;
  }
}

extern "C" void kernel_launch(void* const* d_in, const int* in_sizes, int n_in,
                              void* d_out, int out_size, void* d_ws, size_t ws_size,
                              hipStream_t stream) {
  const float* x    = (const float*)d_in[0];
  const float* W1_0 = (const float*)d_in[1];
  const float* b1_0 = (const float*)d_in[2];
  const float* W2_0 = (const float*)d_in[3];
  const float* b2_0 = (const float*)d_in[4];
  const float* W1_1 = (const float*)d_in[5];
  const float* b1_1 = (const float*)d_in[6];
  const float* W2_1 = (const float*)d_in[7];
  const float* b2_1 = (const float*)d_in[8];
  float* out = (float*)d_out;

  // ws layout: [Wt: 4 x 512KB = 2MB][Y: 16384*2048 bf16 = 64MB]
  unsigned short* Wt = (unsigned short*)d_ws;
  unsigned short* Y  = Wt + 4 * WSZ;

  prep_w_all<<<4096, 256, 0, stream>>>(W1_0, W2_0, W1_1, W2_1, Wt);
  mlp_layer<true ><<<1024, 512, 0, stream>>>(x, Y, Wt, Wt + WSZ, b1_0, b2_0);
  permute_k<<<1024, 256, 0, stream>>>(Y);
  mlp_layer<false><<<1024, 512, 0, stream>>>(nullptr, Y, Wt + 2 * WSZ, Wt + 3 * WSZ, b1_1, b2_1);
  unpermute_k<<<1024, 256, 0, stream>>>(Y, out);
}